// Round 7
// baseline (1104.956 us; speedup 1.0000x reference)
//
#include <hip/hip_runtime.h>
#include <cstdint>

typedef unsigned short u16;
typedef __attribute__((ext_vector_type(8))) short bf16x8;
typedef __attribute__((ext_vector_type(4))) float f32x4;

#define MFMA16(a, b, c) __builtin_amdgcn_mfma_f32_16x16x32_bf16((a), (b), (c), 0, 0, 0)

// ---------------- helpers ----------------
__device__ __forceinline__ u16 f2bf(float f) {
    union { float f; uint32_t u; } v; v.f = f;
    uint32_t r = v.u + 0x7FFFu + ((v.u >> 16) & 1u);  // round-to-nearest-even
    return (u16)(r >> 16);
}

__device__ __forceinline__ void gload_lds16(const void* g, void* l) {
    __builtin_amdgcn_global_load_lds(
        (const __attribute__((address_space(1))) uint32_t*)g,
        (__attribute__((address_space(3))) uint32_t*)l, 16, 0, 0);
}

// ---------------- weight transpose+convert: in (K,N) f32 -> out (N,K) bf16 ----------------
__global__ __launch_bounds__(256)
void transpose_cvt(const float* __restrict__ in, u16* __restrict__ out, int K, int N) {
    __shared__ float t[32][33];
    const int n0 = blockIdx.x * 32, k0 = blockIdx.y * 32;
    const int tx = threadIdx.x, ty = threadIdx.y;  // 32 x 8
#pragma unroll
    for (int i = 0; i < 4; i++)
        t[ty + i * 8][tx] = in[(size_t)(k0 + ty + i * 8) * N + n0 + tx];
    __syncthreads();
#pragma unroll
    for (int i = 0; i < 4; i++)
        out[(size_t)(n0 + ty + i * 8) * K + k0 + tx] = f2bf(t[tx][ty + i * 8]);
}

__global__ void concat_bias(const float* __restrict__ bq, const float* __restrict__ bk,
                            const float* __restrict__ bv, float* __restrict__ o) {
    int i = blockIdx.x * 256 + threadIdx.x;  // 3072
    o[i] = (i < 1024) ? bq[i] : (i < 2048 ? bk[i - 1024] : bv[i - 2048]);
}

// ---------------- adaLN conditioning GEMM: ada[b][j] = c[b] @ W_ada + b_ada ----------------
__global__ __launch_bounds__(256)
void ada_gemm(const float* __restrict__ c, const float* __restrict__ W,
              const float* __restrict__ b, float* __restrict__ ada) {
    __shared__ float cs[4][1024];
    const int tid = threadIdx.x;
    for (int i = tid; i < 4096; i += 256) cs[i >> 10][i & 1023] = c[i];
    __syncthreads();
    const int j = blockIdx.x * 256 + tid;  // < 6144
    float a0 = 0, a1 = 0, a2 = 0, a3 = 0;
    for (int k = 0; k < 1024; k++) {
        float wv = W[(size_t)k * 6144 + j];
        a0 += cs[0][k] * wv; a1 += cs[1][k] * wv; a2 += cs[2][k] * wv; a3 += cs[3][k] * wv;
    }
    float bb = b[j];
    ada[j] = a0 + bb; ada[6144 + j] = a1 + bb;
    ada[2 * 6144 + j] = a2 + bb; ada[3 * 6144 + j] = a3 + bb;
}

// ---------------- LayerNorm + adaLN modulation -> bf16 ----------------
__global__ __launch_bounds__(256)
void ln_mod(const float* __restrict__ x, const float* __restrict__ ada,
            int shift_off, int scale_off, u16* __restrict__ out) {
    const int row = blockIdx.x, tid = threadIdx.x;
    const int b = row >> 11;
    const float4 v = ((const float4*)(x + (size_t)row * 1024))[tid];
    float s1 = v.x + v.y + v.z + v.w;
    float s2 = v.x * v.x + v.y * v.y + v.z * v.z + v.w * v.w;
#pragma unroll
    for (int o = 32; o; o >>= 1) { s1 += __shfl_xor(s1, o); s2 += __shfl_xor(s2, o); }
    __shared__ float red[8];
    if ((tid & 63) == 0) { red[tid >> 6] = s1; red[4 + (tid >> 6)] = s2; }
    __syncthreads();
    s1 = red[0] + red[1] + red[2] + red[3];
    s2 = red[4] + red[5] + red[6] + red[7];
    const float mu = s1 * (1.f / 1024.f);
    const float rs = rsqrtf(s2 * (1.f / 1024.f) - mu * mu + 1e-5f);
    const float4 sh = ((const float4*)(ada + (size_t)b * 6144 + shift_off))[tid];
    const float4 sc = ((const float4*)(ada + (size_t)b * 6144 + scale_off))[tid];
    u16 h0 = f2bf((v.x - mu) * rs * (1.f + sc.x) + sh.x);
    u16 h1 = f2bf((v.y - mu) * rs * (1.f + sc.y) + sh.y);
    u16 h2 = f2bf((v.z - mu) * rs * (1.f + sc.z) + sh.z);
    u16 h3 = f2bf((v.w - mu) * rs * (1.f + sc.w) + sh.w);
    uint2 p;
    p.x = (uint32_t)h0 | ((uint32_t)h1 << 16);
    p.y = (uint32_t)h2 | ((uint32_t)h3 << 16);
    ((uint2*)(out + (size_t)row * 1024))[tid] = p;
}

// ---------------- main GEMM: C = A(M,K) @ BT(N,K)^T, fused epilogues ----------------
// (m97-structure: 128x128 tile, BK=32, global_load_lds width=16, dbuf LDS)
// EPI 0: +bqkv, scatter to Q (B,H,N,64), K (B,H,N,64), V^T (B,H,64,N), bf16
// EPI 1: y = x + gate1*(C+bo), f32
// EPI 2: t = gelu(C+b1), bf16
// EPI 3: out = y + gate2*(C+b2), f32
template <int EPI, int KDIM>
__global__ __launch_bounds__(256)
void gemm_bt(const u16* __restrict__ A, const u16* __restrict__ BT,
             const float* __restrict__ bias, const float* __restrict__ ada,
             const float* __restrict__ resid, float* __restrict__ outF,
             u16* __restrict__ outB, u16* __restrict__ outQ,
             u16* __restrict__ outK, u16* __restrict__ outV) {
    constexpr int GOFF = (EPI == 1) ? 2048 : 5120;  // gate1 / gate2 offset in ada row
    __shared__ u16 lA[2][128 * 32];
    __shared__ u16 lB[2][128 * 32];
    const int tid = threadIdx.x;
    const int w = tid >> 6, l = tid & 63;
    const int lr = l & 15, lg = l >> 4;
    const int wr = w >> 1, wc = w & 1;
    const int bn = blockIdx.x, bm = blockIdx.y;
    const u16* Ab = A + (size_t)bm * 128 * KDIM;
    const u16* Bb = BT + (size_t)bn * 128 * KDIM;
    const int crow = l >> 2;          // row within 16-row staging chunk
    const int ccol = (l & 3) * 8;     // elem col within 32-wide K slice

    f32x4 acc[4][4];
#pragma unroll
    for (int m = 0; m < 4; m++)
#pragma unroll
        for (int n = 0; n < 4; n++) acc[m][n] = (f32x4){0.f, 0.f, 0.f, 0.f};

    // prologue: stage tile 0
#pragma unroll
    for (int i = 0; i < 2; i++) {
        const int cc = w * 2 + i;
        gload_lds16(Ab + (size_t)(cc * 16 + crow) * KDIM + ccol, &lA[0][cc * 512]);
        gload_lds16(Bb + (size_t)(cc * 16 + crow) * KDIM + ccol, &lB[0][cc * 512]);
    }
    constexpr int NT = KDIM / 32;
    for (int kt = 0; kt < NT; ++kt) {
        const int cur = kt & 1;
        __syncthreads();  // tile kt staged (implicit vmcnt(0) drain), prev readers done
        if (kt + 1 < NT) {
#pragma unroll
            for (int i = 0; i < 2; i++) {
                const int cc = w * 2 + i;
                gload_lds16(Ab + (size_t)(cc * 16 + crow) * KDIM + (kt + 1) * 32 + ccol,
                            &lA[cur ^ 1][cc * 512]);
                gload_lds16(Bb + (size_t)(cc * 16 + crow) * KDIM + (kt + 1) * 32 + ccol,
                            &lB[cur ^ 1][cc * 512]);
            }
        }
        bf16x8 af[4], bfr[4];
#pragma unroll
        for (int m = 0; m < 4; m++)
            af[m] = *(const bf16x8*)&lA[cur][(wr * 64 + m * 16 + lr) * 32 + lg * 8];
#pragma unroll
        for (int n = 0; n < 4; n++)
            bfr[n] = *(const bf16x8*)&lB[cur][(wc * 64 + n * 16 + lr) * 32 + lg * 8];
#pragma unroll
        for (int m = 0; m < 4; m++)
#pragma unroll
            for (int n = 0; n < 4; n++) acc[m][n] = MFMA16(af[m], bfr[n], acc[m][n]);
    }

    const int row0 = bm * 128 + wr * 64;
    const int col0 = bn * 128 + wc * 64;
#pragma unroll
    for (int m = 0; m < 4; m++) {
#pragma unroll
        for (int n = 0; n < 4; n++) {
#pragma unroll
            for (int r = 0; r < 4; r++) {
                const int grow = row0 + m * 16 + lg * 4 + r;
                const int gcol = col0 + n * 16 + lr;
                float val = acc[m][n][r] + bias[gcol];
                if (EPI == 0) {
                    const int seg = gcol >> 10, j = gcol & 1023;
                    const int hh = j >> 6, d = j & 63;
                    const int bi = grow >> 11, nn = grow & 2047;
                    const size_t head = (size_t)bi * 16 + hh;
                    if (seg == 0)      outQ[(head * 2048 + nn) * 64 + d] = f2bf(val);
                    else if (seg == 1) outK[(head * 2048 + nn) * 64 + d] = f2bf(val);
                    else               outV[(head * 64 + d) * 2048 + nn] = f2bf(val);
                } else if (EPI == 2) {
                    const float gl = 0.5f * val * (1.f + erff(val * 0.70710678f));
                    outB[(size_t)grow * 4096 + gcol] = f2bf(gl);
                } else {
                    const int bi = grow >> 11;
                    const float g = ada[(size_t)bi * 6144 + GOFF + gcol];
                    outF[(size_t)grow * 1024 + gcol] =
                        resid[(size_t)grow * 1024 + gcol] + g * val;
                }
            }
        }
    }
}

// ---------------- flash attention: 4 waves x 16 q-rows, KV tile 64 ----------------
// waves are independent (no block barriers) -> T5 setprio regime (m191: +4-7%)
__global__ __launch_bounds__(256)
void attn_fwd(const u16* __restrict__ Q, const u16* __restrict__ K,
              const u16* __restrict__ Vt, u16* __restrict__ O) {
    const int tid = threadIdx.x;
    const int w = tid >> 6, l = tid & 63;
    const int lr = l & 15, lg = l >> 4;
    const int qt = blockIdx.x, hh = blockIdx.y, bi = blockIdx.z;
    const size_t head = (size_t)bi * 16 + hh;
    const u16* Qh = Q + head * 2048 * 64;
    const u16* Kh = K + head * 2048 * 64;
    const u16* Vh = Vt + head * 64 * 2048;  // (64 d, 2048 n)
    const int q0 = qt * 64 + w * 16;

    bf16x8 aq[2];
    aq[0] = *(const bf16x8*)(Qh + (size_t)(q0 + lr) * 64 + lg * 8);
    aq[1] = *(const bf16x8*)(Qh + (size_t)(q0 + lr) * 64 + 32 + lg * 8);

    __shared__ u16 Pl[4][16 * 80];  // per-wave P buffer, padded to 80 elems/row
    u16* Pw = Pl[w];

    f32x4 acco[4];
#pragma unroll
    for (int d = 0; d < 4; d++) acco[d] = (f32x4){0.f, 0.f, 0.f, 0.f};
    float m[4], ssum[4];
#pragma unroll
    for (int r = 0; r < 4; r++) { m[r] = -1e30f; ssum[r] = 0.f; }

    for (int k0 = 0; k0 < 2048; k0 += 64) {
        f32x4 s[4];
#pragma unroll
        for (int c = 0; c < 4; c++) s[c] = (f32x4){0.f, 0.f, 0.f, 0.f};
        __builtin_amdgcn_s_setprio(1);
#pragma unroll
        for (int c = 0; c < 4; c++) {
            const u16* kp = Kh + (size_t)(k0 + c * 16 + lr) * 64 + lg * 8;
            s[c] = MFMA16(aq[0], *(const bf16x8*)kp, s[c]);
            s[c] = MFMA16(aq[1], *(const bf16x8*)(kp + 32), s[c]);
        }
        __builtin_amdgcn_s_setprio(0);
        // scale 1/sqrt(64)
#pragma unroll
        for (int c = 0; c < 4; c++)
#pragma unroll
            for (int r = 0; r < 4; r++) s[c][r] *= 0.125f;
        // online softmax (rows owned by 16-lane groups; reduce over low 4 lane bits)
        float al[4];
#pragma unroll
        for (int r = 0; r < 4; r++) {
            float t = fmaxf(fmaxf(s[0][r], s[1][r]), fmaxf(s[2][r], s[3][r]));
#pragma unroll
            for (int o = 1; o < 16; o <<= 1) t = fmaxf(t, __shfl_xor(t, o));
            const float mn = fmaxf(m[r], t);
            al[r] = __expf(m[r] - mn);
            m[r] = mn;
            ssum[r] *= al[r];
        }
#pragma unroll
        for (int d = 0; d < 4; d++)
#pragma unroll
            for (int r = 0; r < 4; r++) acco[d][r] *= al[r];
#pragma unroll
        for (int c = 0; c < 4; c++)
#pragma unroll
            for (int r = 0; r < 4; r++) {
                const float p = __expf(s[c][r] - m[r]);
                s[c][r] = p;
                ssum[r] += p;
            }
        // P -> LDS (bf16), then read back as MFMA A fragments (same-wave, compiler
        // inserts lgkmcnt; no barrier needed — per-wave buffer)
#pragma unroll
        for (int c = 0; c < 4; c++)
#pragma unroll
            for (int r = 0; r < 4; r++)
                Pw[(lg * 4 + r) * 80 + c * 16 + lr] = f2bf(s[c][r]);
        const bf16x8 ap0 = *(const bf16x8*)(Pw + lr * 80 + lg * 8);
        const bf16x8 ap1 = *(const bf16x8*)(Pw + lr * 80 + 32 + lg * 8);
        __builtin_amdgcn_s_setprio(1);
#pragma unroll
        for (int dt = 0; dt < 4; dt++) {
            const u16* vp = Vh + (size_t)(dt * 16 + lr) * 2048 + k0 + lg * 8;
            acco[dt] = MFMA16(ap0, *(const bf16x8*)vp, acco[dt]);
            acco[dt] = MFMA16(ap1, *(const bf16x8*)(vp + 32), acco[dt]);
        }
        __builtin_amdgcn_s_setprio(0);
    }
#pragma unroll
    for (int r = 0; r < 4; r++) {
        float t = ssum[r];
#pragma unroll
        for (int o = 1; o < 16; o <<= 1) t += __shfl_xor(t, o);
        ssum[r] = 1.f / t;
    }
#pragma unroll
    for (int dt = 0; dt < 4; dt++)
#pragma unroll
        for (int r = 0; r < 4; r++) {
            const float val = acco[dt][r] * ssum[r];
            O[((size_t)bi * 2048 + q0 + lg * 4 + r) * 1024 + hh * 64 + dt * 16 + lr] =
                f2bf(val);
        }
}

// ---------------- workspace layout (bytes) ----------------
#define ADA_OFF   0UL               // 4*6144*4      = 98304
#define BQKV_OFF  98304UL           // 3072*4        = 12288
#define WQKV_OFF  110592UL          // 3072*1024*2   = 6291456
#define WO_OFF    6402048UL         // 1024*1024*2   = 2097152
#define W1T_OFF   8499200UL         // 4096*1024*2   = 8388608
#define W2T_OFF   16887808UL        // 1024*4096*2   = 8388608
#define Y_OFF     25276416UL        // 8192*1024*4   = 33554432
#define H_OFF     58830848UL        // 8192*1024*2   = 16777216 (h1 & h2)
#define QB_OFF    75608064UL        // 16777216
#define KB_OFF    92385280UL        // 16777216
#define VT_OFF    109162496UL       // 16777216
#define ATT_OFF   125939712UL       // 16777216
#define T_OFF     QB_OFF            // 8192*4096*2 = 67108864, overlays Q/K/Vt/att (dead)
// total: 142716928 bytes (~136 MiB)

extern "C" void kernel_launch(void* const* d_in, const int* in_sizes, int n_in,
                              void* d_out, int out_size, void* d_ws, size_t ws_size,
                              hipStream_t stream) {
    (void)in_sizes; (void)n_in; (void)out_size; (void)ws_size;
    const float* x    = (const float*)d_in[0];
    const float* c    = (const float*)d_in[1];
    const float* Wada = (const float*)d_in[2];
    const float* bada = (const float*)d_in[3];
    const float* Wq   = (const float*)d_in[4];
    const float* bq   = (const float*)d_in[5];
    const float* Wk   = (const float*)d_in[6];
    const float* bk   = (const float*)d_in[7];
    const float* Wv   = (const float*)d_in[8];
    const float* bv   = (const float*)d_in[9];
    const float* Wo   = (const float*)d_in[10];
    const float* bo   = (const float*)d_in[11];
    const float* W1   = (const float*)d_in[12];
    const float* b1   = (const float*)d_in[13];
    const float* W2   = (const float*)d_in[14];
    const float* b2   = (const float*)d_in[15];
    float* outp = (float*)d_out;

    char* ws = (char*)d_ws;
    float* ada  = (float*)(ws + ADA_OFF);
    float* bqkv = (float*)(ws + BQKV_OFF);
    u16* wqkvT  = (u16*)(ws + WQKV_OFF);
    u16* woT    = (u16*)(ws + WO_OFF);
    u16* w1T    = (u16*)(ws + W1T_OFF);
    u16* w2T    = (u16*)(ws + W2T_OFF);
    float* y    = (float*)(ws + Y_OFF);
    u16* hbuf   = (u16*)(ws + H_OFF);
    u16* qb     = (u16*)(ws + QB_OFF);
    u16* kb     = (u16*)(ws + KB_OFF);
    u16* vt     = (u16*)(ws + VT_OFF);
    u16* attb   = (u16*)(ws + ATT_OFF);
    u16* tbuf   = (u16*)(ws + T_OFF);

    const dim3 tb32(32, 8);
    // weight prep
    transpose_cvt<<<dim3(32, 32), tb32, 0, stream>>>(Wq, wqkvT, 1024, 1024);
    transpose_cvt<<<dim3(32, 32), tb32, 0, stream>>>(Wk, wqkvT + 1024 * 1024, 1024, 1024);
    transpose_cvt<<<dim3(32, 32), tb32, 0, stream>>>(Wv, wqkvT + 2 * 1024 * 1024, 1024, 1024);
    transpose_cvt<<<dim3(32, 32), tb32, 0, stream>>>(Wo, woT, 1024, 1024);
    transpose_cvt<<<dim3(128, 32), tb32, 0, stream>>>(W1, w1T, 1024, 4096);
    transpose_cvt<<<dim3(32, 128), tb32, 0, stream>>>(W2, w2T, 4096, 1024);
    concat_bias<<<12, 256, 0, stream>>>(bq, bk, bv, bqkv);
    // conditioning
    ada_gemm<<<24, 256, 0, stream>>>(c, Wada, bada, ada);
    // attention branch
    ln_mod<<<8192, 256, 0, stream>>>(x, ada, 0, 1024, hbuf);
    gemm_bt<0, 1024><<<dim3(24, 64), 256, 0, stream>>>(
        hbuf, wqkvT, bqkv, nullptr, nullptr, nullptr, nullptr, qb, kb, vt);
    attn_fwd<<<dim3(32, 16, 4), 256, 0, stream>>>(qb, kb, vt, attb);
    gemm_bt<1, 1024><<<dim3(8, 64), 256, 0, stream>>>(
        attb, woT, bo, ada, x, y, nullptr, nullptr, nullptr, nullptr);
    // FFN branch
    ln_mod<<<8192, 256, 0, stream>>>(y, ada, 3 * 1024, 4 * 1024, hbuf);
    gemm_bt<2, 1024><<<dim3(32, 64), 256, 0, stream>>>(
        hbuf, w1T, b1, nullptr, nullptr, nullptr, tbuf, nullptr, nullptr, nullptr);
    gemm_bt<3, 4096><<<dim3(8, 64), 256, 0, stream>>>(
        tbuf, w2T, b2, ada, y, outp, nullptr, nullptr, nullptr, nullptr);
}

// Round 10
// 841.450 us; speedup vs baseline: 1.3132x; 1.3132x over previous
//
#include <hip/hip_runtime.h>
#include <cstdint>

typedef unsigned short u16;
typedef __attribute__((ext_vector_type(8))) short bf16x8;
typedef __attribute__((ext_vector_type(4))) float f32x4;

#define MFMA16(a, b, c) __builtin_amdgcn_mfma_f32_16x16x32_bf16((a), (b), (c), 0, 0, 0)

// ---------------- helpers ----------------
__device__ __forceinline__ u16 f2bf(float f) {
    union { float f; uint32_t u; } v; v.f = f;
    uint32_t r = v.u + 0x7FFFu + ((v.u >> 16) & 1u);  // round-to-nearest-even
    return (u16)(r >> 16);
}

__device__ __forceinline__ void gload_lds16(const void* g, void* l) {
    __builtin_amdgcn_global_load_lds(
        (const __attribute__((address_space(1))) uint32_t*)g,
        (__attribute__((address_space(3))) uint32_t*)l, 16, 0, 0);
}

// ---------------- weight transpose+convert: in (K,N) f32 -> out (N,K) bf16 ----------------
__global__ __launch_bounds__(256)
void transpose_cvt(const float* __restrict__ in, u16* __restrict__ out, int K, int N) {
    __shared__ float t[32][33];
    const int n0 = blockIdx.x * 32, k0 = blockIdx.y * 32;
    const int tx = threadIdx.x, ty = threadIdx.y;  // 32 x 8
#pragma unroll
    for (int i = 0; i < 4; i++)
        t[ty + i * 8][tx] = in[(size_t)(k0 + ty + i * 8) * N + n0 + tx];
    __syncthreads();
#pragma unroll
    for (int i = 0; i < 4; i++)
        out[(size_t)(n0 + ty + i * 8) * K + k0 + tx] = f2bf(t[tx][ty + i * 8]);
}

__global__ void concat_bias(const float* __restrict__ bq, const float* __restrict__ bk,
                            const float* __restrict__ bv, float* __restrict__ o) {
    int i = blockIdx.x * 256 + threadIdx.x;  // 3072
    o[i] = (i < 1024) ? bq[i] : (i < 2048 ? bk[i - 1024] : bv[i - 2048]);
}

// ---------------- adaLN conditioning GEMM: ada[b][j] = c[b] @ W_ada + b_ada ----------------
__global__ __launch_bounds__(256)
void ada_gemm(const float* __restrict__ c, const float* __restrict__ W,
              const float* __restrict__ b, float* __restrict__ ada) {
    __shared__ float cs[4][1024];
    const int tid = threadIdx.x;
    for (int i = tid; i < 4096; i += 256) cs[i >> 10][i & 1023] = c[i];
    __syncthreads();
    const int j = blockIdx.x * 256 + tid;  // < 6144
    float a0 = 0, a1 = 0, a2 = 0, a3 = 0;
    for (int k = 0; k < 1024; k++) {
        float wv = W[(size_t)k * 6144 + j];
        a0 += cs[0][k] * wv; a1 += cs[1][k] * wv; a2 += cs[2][k] * wv; a3 += cs[3][k] * wv;
    }
    float bb = b[j];
    ada[j] = a0 + bb; ada[6144 + j] = a1 + bb;
    ada[2 * 6144 + j] = a2 + bb; ada[3 * 6144 + j] = a3 + bb;
}

// ---------------- LayerNorm + adaLN modulation -> bf16 ----------------
__global__ __launch_bounds__(256)
void ln_mod(const float* __restrict__ x, const float* __restrict__ ada,
            int shift_off, int scale_off, u16* __restrict__ out) {
    const int row = blockIdx.x, tid = threadIdx.x;
    const int b = row >> 11;
    const float4 v = ((const float4*)(x + (size_t)row * 1024))[tid];
    float s1 = v.x + v.y + v.z + v.w;
    float s2 = v.x * v.x + v.y * v.y + v.z * v.z + v.w * v.w;
#pragma unroll
    for (int o = 32; o; o >>= 1) { s1 += __shfl_xor(s1, o); s2 += __shfl_xor(s2, o); }
    __shared__ float red[8];
    if ((tid & 63) == 0) { red[tid >> 6] = s1; red[4 + (tid >> 6)] = s2; }
    __syncthreads();
    s1 = red[0] + red[1] + red[2] + red[3];
    s2 = red[4] + red[5] + red[6] + red[7];
    const float mu = s1 * (1.f / 1024.f);
    const float rs = rsqrtf(s2 * (1.f / 1024.f) - mu * mu + 1e-5f);
    const float4 sh = ((const float4*)(ada + (size_t)b * 6144 + shift_off))[tid];
    const float4 sc = ((const float4*)(ada + (size_t)b * 6144 + scale_off))[tid];
    u16 h0 = f2bf((v.x - mu) * rs * (1.f + sc.x) + sh.x);
    u16 h1 = f2bf((v.y - mu) * rs * (1.f + sc.y) + sh.y);
    u16 h2 = f2bf((v.z - mu) * rs * (1.f + sc.z) + sh.z);
    u16 h3 = f2bf((v.w - mu) * rs * (1.f + sc.w) + sh.w);
    uint2 p;
    p.x = (uint32_t)h0 | ((uint32_t)h1 << 16);
    p.y = (uint32_t)h2 | ((uint32_t)h3 << 16);
    ((uint2*)(out + (size_t)row * 1024))[tid] = p;
}

// ---------------- main GEMM: C = A(M,K) @ BT(N,K)^T, fused epilogues ----------------
// (m97-structure: 128x128 tile, BK=32, global_load_lds width=16, dbuf LDS)
// EPI 0: +bqkv, scatter to Q (B,H,N,64), K (B,H,N,64), V^T (B,H,64,N), bf16
// EPI 1: y = x + gate1*(C+bo), f32
// EPI 2: t = gelu(C+b1), bf16
// EPI 3: out = y + gate2*(C+b2), f32
template <int EPI, int KDIM>
__global__ __launch_bounds__(256)
void gemm_bt(const u16* __restrict__ A, const u16* __restrict__ BT,
             const float* __restrict__ bias, const float* __restrict__ ada,
             const float* __restrict__ resid, float* __restrict__ outF,
             u16* __restrict__ outB, u16* __restrict__ outQ,
             u16* __restrict__ outK, u16* __restrict__ outV) {
    constexpr int GOFF = (EPI == 1) ? 2048 : 5120;  // gate1 / gate2 offset in ada row
    __shared__ u16 lA[2][128 * 32];
    __shared__ u16 lB[2][128 * 32];
    const int tid = threadIdx.x;
    const int w = tid >> 6, l = tid & 63;
    const int lr = l & 15, lg = l >> 4;
    const int wr = w >> 1, wc = w & 1;
    const int bn = blockIdx.x, bm = blockIdx.y;
    const u16* Ab = A + (size_t)bm * 128 * KDIM;
    const u16* Bb = BT + (size_t)bn * 128 * KDIM;
    const int crow = l >> 2;          // row within 16-row staging chunk
    const int ccol = (l & 3) * 8;     // elem col within 32-wide K slice

    f32x4 acc[4][4];
#pragma unroll
    for (int m = 0; m < 4; m++)
#pragma unroll
        for (int n = 0; n < 4; n++) acc[m][n] = (f32x4){0.f, 0.f, 0.f, 0.f};

    // prologue: stage tile 0
#pragma unroll
    for (int i = 0; i < 2; i++) {
        const int cc = w * 2 + i;
        gload_lds16(Ab + (size_t)(cc * 16 + crow) * KDIM + ccol, &lA[0][cc * 512]);
        gload_lds16(Bb + (size_t)(cc * 16 + crow) * KDIM + ccol, &lB[0][cc * 512]);
    }
    constexpr int NT = KDIM / 32;
    for (int kt = 0; kt < NT; ++kt) {
        const int cur = kt & 1;
        __syncthreads();  // tile kt staged (implicit vmcnt(0) drain), prev readers done
        if (kt + 1 < NT) {
#pragma unroll
            for (int i = 0; i < 2; i++) {
                const int cc = w * 2 + i;
                gload_lds16(Ab + (size_t)(cc * 16 + crow) * KDIM + (kt + 1) * 32 + ccol,
                            &lA[cur ^ 1][cc * 512]);
                gload_lds16(Bb + (size_t)(cc * 16 + crow) * KDIM + (kt + 1) * 32 + ccol,
                            &lB[cur ^ 1][cc * 512]);
            }
        }
        bf16x8 af[4], bfr[4];
#pragma unroll
        for (int m = 0; m < 4; m++)
            af[m] = *(const bf16x8*)&lA[cur][(wr * 64 + m * 16 + lr) * 32 + lg * 8];
#pragma unroll
        for (int n = 0; n < 4; n++)
            bfr[n] = *(const bf16x8*)&lB[cur][(wc * 64 + n * 16 + lr) * 32 + lg * 8];
#pragma unroll
        for (int m = 0; m < 4; m++)
#pragma unroll
            for (int n = 0; n < 4; n++) acc[m][n] = MFMA16(af[m], bfr[n], acc[m][n]);
    }

    const int row0 = bm * 128 + wr * 64;
    const int col0 = bn * 128 + wc * 64;
#pragma unroll
    for (int m = 0; m < 4; m++) {
#pragma unroll
        for (int n = 0; n < 4; n++) {
#pragma unroll
            for (int r = 0; r < 4; r++) {
                const int grow = row0 + m * 16 + lg * 4 + r;
                const int gcol = col0 + n * 16 + lr;
                float val = acc[m][n][r] + bias[gcol];
                if (EPI == 0) {
                    const int seg = gcol >> 10, j = gcol & 1023;
                    const int hh = j >> 6, d = j & 63;
                    const int bi = grow >> 11, nn = grow & 2047;
                    const size_t head = (size_t)bi * 16 + hh;
                    if (seg == 0)      outQ[(head * 2048 + nn) * 64 + d] = f2bf(val);
                    else if (seg == 1) outK[(head * 2048 + nn) * 64 + d] = f2bf(val);
                    else               outV[(head * 64 + d) * 2048 + nn] = f2bf(val);
                } else if (EPI == 2) {
                    const float gl = 0.5f * val * (1.f + erff(val * 0.70710678f));
                    outB[(size_t)grow * 4096 + gcol] = f2bf(gl);
                } else {
                    const int bi = grow >> 11;
                    const float g = ada[(size_t)bi * 6144 + GOFF + gcol];
                    outF[(size_t)grow * 1024 + gcol] =
                        resid[(size_t)grow * 1024 + gcol] + g * val;
                }
            }
        }
    }
}

// ---------------- flash attention: 4 waves x 16 q-rows, KV tile 64 ----------------
// r8: K/V LDS-staged (dbuf, gload_lds 16B, prefetch next tile), XOR-swizzled
// (linear dest + inverse-swz global source + swz read, rule #21); P pad 72
// (2-way instead of 4-way); T13 defer-max; setprio removed (now lockstep).
__global__ __launch_bounds__(256)
void attn_fwd(const u16* __restrict__ Q, const u16* __restrict__ K,
              const u16* __restrict__ Vt, u16* __restrict__ O) {
    const int tid = threadIdx.x;
    const int w = tid >> 6, l = tid & 63;
    const int lr = l & 15, lg = l >> 4;
    const int qt = blockIdx.x, hh = blockIdx.y, bi = blockIdx.z;
    const size_t head = (size_t)bi * 16 + hh;
    const u16* Qh = Q + head * 2048 * 64;
    const u16* Kh = K + head * 2048 * 64;
    const u16* Vh = Vt + head * 64 * 2048;  // (64 d, 2048 n)
    const int q0 = qt * 64 + w * 16;

    __shared__ u16 Kl[2][64 * 64];   // [buf][row*64 + col], 16B-chunk swizzled
    __shared__ u16 Vl[2][64 * 64];   // rows are d, cols are kv
    __shared__ u16 Pl[4][16 * 72];   // per-wave P, pad 72 (stride 144B -> 2-way)
    u16* Pw = Pl[w];

    bf16x8 aq[2];
    aq[0] = *(const bf16x8*)(Qh + (size_t)(q0 + lr) * 64 + lg * 8);
    aq[1] = *(const bf16x8*)(Qh + (size_t)(q0 + lr) * 64 + 32 + lg * 8);

    // staging geometry: per wave, 16 rows x 128B in 2 gload_lds; lane covers
    // row i*8+(l>>3), chunk l&7; source chunk ^= row&7 (inverse swizzle)
    const int srow = l >> 3;   // 0..7
    const int schunk = l & 7;  // 0..7

    f32x4 acco[4];
#pragma unroll
    for (int d = 0; d < 4; d++) acco[d] = (f32x4){0.f, 0.f, 0.f, 0.f};
    float m[4], ssum[4];
#pragma unroll
    for (int r = 0; r < 4; r++) { m[r] = -1e30f; ssum[r] = 0.f; }

    // prologue: stage tile 0 into buf 0
#pragma unroll
    for (int i = 0; i < 2; i++) {
        const int row = w * 16 + i * 8 + srow;
        gload_lds16(Kh + (size_t)row * 64 + ((schunk ^ (row & 7)) * 8),
                    &Kl[0][(w * 16 + i * 8) * 64]);
        gload_lds16(Vh + (size_t)row * 2048 + ((schunk ^ (row & 7)) * 8),
                    &Vl[0][(w * 16 + i * 8) * 64]);
    }

    for (int t = 0; t < 32; ++t) {
        const int buf = t & 1;
        __syncthreads();  // tile t staged (vmcnt drained at barrier); buf^1 free
        if (t + 1 < 32) {
            const int k1 = (t + 1) * 64;
#pragma unroll
            for (int i = 0; i < 2; i++) {
                const int row = w * 16 + i * 8 + srow;
                gload_lds16(Kh + (size_t)(k1 + row) * 64 + ((schunk ^ (row & 7)) * 8),
                            &Kl[buf ^ 1][(w * 16 + i * 8) * 64]);
                gload_lds16(Vh + (size_t)row * 2048 + k1 + ((schunk ^ (row & 7)) * 8),
                            &Vl[buf ^ 1][(w * 16 + i * 8) * 64]);
            }
        }
        // QK^T from swizzled LDS
        f32x4 s[4];
#pragma unroll
        for (int c = 0; c < 4; c++) s[c] = (f32x4){0.f, 0.f, 0.f, 0.f};
#pragma unroll
        for (int c = 0; c < 4; c++) {
            const int kr = c * 16 + lr;
            const bf16x8 kf0 = *(const bf16x8*)&Kl[buf][kr * 64 + ((lg ^ (kr & 7)) * 8)];
            const bf16x8 kf1 = *(const bf16x8*)&Kl[buf][kr * 64 + (((4 + lg) ^ (kr & 7)) * 8)];
            s[c] = MFMA16(aq[0], kf0, s[c]);
            s[c] = MFMA16(aq[1], kf1, s[c]);
        }
#pragma unroll
        for (int c = 0; c < 4; c++)
#pragma unroll
            for (int r = 0; r < 4; r++) s[c][r] *= 0.125f;  // 1/sqrt(64)
        // online softmax; rows owned by 16-lane groups, reduce over low 4 lane bits
        float tmax[4];
#pragma unroll
        for (int r = 0; r < 4; r++) {
            float tv = fmaxf(fmaxf(s[0][r], s[1][r]), fmaxf(s[2][r], s[3][r]));
#pragma unroll
            for (int o = 1; o < 16; o <<= 1) tv = fmaxf(tv, __shfl_xor(tv, o));
            tmax[r] = tv;
        }
        // T13 defer-max: skip O/sum rescale while max growth <= 8 (P <= e^8, safe)
        const bool need = (tmax[0] > m[0] + 8.f) || (tmax[1] > m[1] + 8.f) ||
                          (tmax[2] > m[2] + 8.f) || (tmax[3] > m[3] + 8.f);
        if (__any(need)) {
            float al[4];
#pragma unroll
            for (int r = 0; r < 4; r++) {
                const float mn = fmaxf(m[r], tmax[r]);
                al[r] = __expf(m[r] - mn);
                m[r] = mn;
                ssum[r] *= al[r];
            }
#pragma unroll
            for (int d = 0; d < 4; d++)
#pragma unroll
                for (int r = 0; r < 4; r++) acco[d][r] *= al[r];
        }
#pragma unroll
        for (int c = 0; c < 4; c++)
#pragma unroll
            for (int r = 0; r < 4; r++) {
                const float p = __expf(s[c][r] - m[r]);
                s[c][r] = p;
                ssum[r] += p;
            }
        // P -> LDS (bf16), read back as MFMA A fragments (same-wave, no barrier)
#pragma unroll
        for (int c = 0; c < 4; c++)
#pragma unroll
            for (int r = 0; r < 4; r++)
                Pw[(lg * 4 + r) * 72 + c * 16 + lr] = f2bf(s[c][r]);
        const bf16x8 ap0 = *(const bf16x8*)(Pw + lr * 72 + lg * 8);
        const bf16x8 ap1 = *(const bf16x8*)(Pw + lr * 72 + 32 + lg * 8);
        // PV from swizzled LDS V-tile (rows d, cols kv)
#pragma unroll
        for (int dt = 0; dt < 4; dt++) {
            const int vr = dt * 16 + lr;
            const bf16x8 vf0 = *(const bf16x8*)&Vl[buf][vr * 64 + ((lg ^ (vr & 7)) * 8)];
            const bf16x8 vf1 = *(const bf16x8*)&Vl[buf][vr * 64 + (((4 + lg) ^ (vr & 7)) * 8)];
            acco[dt] = MFMA16(ap0, vf0, acco[dt]);
            acco[dt] = MFMA16(ap1, vf1, acco[dt]);
        }
    }
#pragma unroll
    for (int r = 0; r < 4; r++) {
        float tv = ssum[r];
#pragma unroll
        for (int o = 1; o < 16; o <<= 1) tv += __shfl_xor(tv, o);
        ssum[r] = 1.f / tv;
    }
#pragma unroll
    for (int dt = 0; dt < 4; dt++)
#pragma unroll
        for (int r = 0; r < 4; r++) {
            const float val = acco[dt][r] * ssum[r];
            O[((size_t)bi * 2048 + q0 + lg * 4 + r) * 1024 + hh * 64 + dt * 16 + lr] =
                f2bf(val);
        }
}

// ---------------- workspace layout (bytes) ----------------
#define ADA_OFF   0UL               // 4*6144*4      = 98304
#define BQKV_OFF  98304UL           // 3072*4        = 12288
#define WQKV_OFF  110592UL          // 3072*1024*2   = 6291456
#define WO_OFF    6402048UL         // 1024*1024*2   = 2097152
#define W1T_OFF   8499200UL         // 4096*1024*2   = 8388608
#define W2T_OFF   16887808UL        // 1024*4096*2   = 8388608
#define Y_OFF     25276416UL        // 8192*1024*4   = 33554432
#define H_OFF     58830848UL        // 8192*1024*2   = 16777216 (h1 & h2)
#define QB_OFF    75608064UL        // 16777216
#define KB_OFF    92385280UL        // 16777216
#define VT_OFF    109162496UL       // 16777216
#define ATT_OFF   125939712UL       // 16777216
#define T_OFF     QB_OFF            // 8192*4096*2 = 67108864, overlays Q/K/Vt/att (dead)
// total: 142716928 bytes (~136 MiB)

extern "C" void kernel_launch(void* const* d_in, const int* in_sizes, int n_in,
                              void* d_out, int out_size, void* d_ws, size_t ws_size,
                              hipStream_t stream) {
    (void)in_sizes; (void)n_in; (void)out_size; (void)ws_size;
    const float* x    = (const float*)d_in[0];
    const float* c    = (const float*)d_in[1];
    const float* Wada = (const float*)d_in[2];
    const float* bada = (const float*)d_in[3];
    const float* Wq   = (const float*)d_in[4];
    const float* bq   = (const float*)d_in[5];
    const float* Wk   = (const float*)d_in[6];
    const float* bk   = (const float*)d_in[7];
    const float* Wv   = (const float*)d_in[8];
    const float* bv   = (const float*)d_in[9];
    const float* Wo   = (const float*)d_in[10];
    const float* bo   = (const float*)d_in[11];
    const float* W1   = (const float*)d_in[12];
    const float* b1   = (const float*)d_in[13];
    const float* W2   = (const float*)d_in[14];
    const float* b2   = (const float*)d_in[15];
    float* outp = (float*)d_out;

    char* ws = (char*)d_ws;
    float* ada  = (float*)(ws + ADA_OFF);
    float* bqkv = (float*)(ws + BQKV_OFF);
    u16* wqkvT  = (u16*)(ws + WQKV_OFF);
    u16* woT    = (u16*)(ws + WO_OFF);
    u16* w1T    = (u16*)(ws + W1T_OFF);
    u16* w2T    = (u16*)(ws + W2T_OFF);
    float* y    = (float*)(ws + Y_OFF);
    u16* hbuf   = (u16*)(ws + H_OFF);
    u16* qb     = (u16*)(ws + QB_OFF);
    u16* kb     = (u16*)(ws + KB_OFF);
    u16* vt     = (u16*)(ws + VT_OFF);
    u16* attb   = (u16*)(ws + ATT_OFF);
    u16* tbuf   = (u16*)(ws + T_OFF);

    const dim3 tb32(32, 8);
    // weight prep
    transpose_cvt<<<dim3(32, 32), tb32, 0, stream>>>(Wq, wqkvT, 1024, 1024);
    transpose_cvt<<<dim3(32, 32), tb32, 0, stream>>>(Wk, wqkvT + 1024 * 1024, 1024, 1024);
    transpose_cvt<<<dim3(32, 32), tb32, 0, stream>>>(Wv, wqkvT + 2 * 1024 * 1024, 1024, 1024);
    transpose_cvt<<<dim3(32, 32), tb32, 0, stream>>>(Wo, woT, 1024, 1024);
    transpose_cvt<<<dim3(128, 32), tb32, 0, stream>>>(W1, w1T, 1024, 4096);
    transpose_cvt<<<dim3(32, 128), tb32, 0, stream>>>(W2, w2T, 4096, 1024);
    concat_bias<<<12, 256, 0, stream>>>(bq, bk, bv, bqkv);
    // conditioning
    ada_gemm<<<24, 256, 0, stream>>>(c, Wada, bada, ada);
    // attention branch
    ln_mod<<<8192, 256, 0, stream>>>(x, ada, 0, 1024, hbuf);
    gemm_bt<0, 1024><<<dim3(24, 64), 256, 0, stream>>>(
        hbuf, wqkvT, bqkv, nullptr, nullptr, nullptr, nullptr, qb, kb, vt);
    attn_fwd<<<dim3(32, 16, 4), 256, 0, stream>>>(qb, kb, vt, attb);
    gemm_bt<1, 1024><<<dim3(8, 64), 256, 0, stream>>>(
        attb, woT, bo, ada, x, y, nullptr, nullptr, nullptr, nullptr);
    // FFN branch
    ln_mod<<<8192, 256, 0, stream>>>(y, ada, 3 * 1024, 4 * 1024, hbuf);
    gemm_bt<2, 1024><<<dim3(32, 64), 256, 0, stream>>>(
        hbuf, w1T, b1, nullptr, nullptr, nullptr, tbuf, nullptr, nullptr, nullptr);
    gemm_bt<3, 4096><<<dim3(8, 64), 256, 0, stream>>>(
        tbuf, w2T, b2, ada, y, outp, nullptr, nullptr, nullptr, nullptr);
}